// Round 5
// baseline (229.275 us; speedup 1.0000x reference)
//
#include <hip/hip_runtime.h>
#include <cmath>

constexpr int N_NODES = 50000;
constexpr int N_EDGES = 800000;
constexpr int D = 128;
constexpr int CAP = 32;           // bucket capacity (Poisson(16); ovf fallback)
constexpr int OVF_CAP = 8192;

constexpr int EPB = 2048;                                  // edges per scatter block
constexpr int SCAT_BLOCKS = (N_EDGES + EPB - 1) / EPB;     // 391 (single pass)
constexpr int CAST_BLOCKS = (N_NODES * D / 8 + 255) / 256; // 3125 (uint4/thread)

// ---- workspace layout (bytes) ----
// cnt     : int[N_NODES]        @ 0            (200,000)
// ovf_cnt : int                 @ 200,000
// bucket  : uint[N_NODES*CAP]   @ 200,064      (6,400,000)
// ovf     : int4[OVF_CAP]       @ 6,600,064    (131,072)
// packed  : uint[N_NODES*D/2]   @ 6,731,136    (12,800,000) -> end 19,531,136
constexpr size_t OFF_OVFCNT = 200000;
constexpr size_t OFF_BUCKET = 200064;
constexpr size_t OFF_OVF    = 6600064;
constexpr size_t OFF_PACKED = 6731136;

typedef __attribute__((ext_vector_type(8))) short bf16x8;
typedef __attribute__((ext_vector_type(4))) float f32x4;

__device__ __forceinline__ unsigned bf16rn(float f) {
    unsigned u = __float_as_uint(f);
    return (u + 0x7fffu + ((u >> 16) & 1u)) >> 16;   // round-to-nearest-even
}
__device__ __forceinline__ float bf_lo(unsigned u) { return __uint_as_float(u << 16); }
__device__ __forceinline__ float bf_hi(unsigned u) { return __uint_as_float(u & 0xffff0000u); }

// val in [0, 1/16) -> 16-bit fixed point (x 2^20). quant step 2^-20.
__device__ __forceinline__ unsigned enc_val(float v) {
    int m = (int)(v * 1048576.0f + 0.5f);
    if (m > 65535) m = 65535;
    if (m < 0) m = 0;
    return (unsigned)m;
}

__device__ __forceinline__ void push_edge(
    int r, int c, float v,
    int* __restrict__ cnt, unsigned* __restrict__ bucket,
    int* __restrict__ ovf_cnt, int4* __restrict__ ovf)
{
    unsigned ent = (unsigned)c | (enc_val(v) << 16);
    int pos = atomicAdd(&cnt[r], 1);
    if (pos < CAP) bucket[(size_t)r * CAP + pos] = ent;
    else {
        int o = atomicAdd(ovf_cnt, 1);
        if (o < OVF_CAP) ovf[o] = make_int4(r, c, __float_as_int(v), 0);
    }
}

// ---------------------------------------------------------------------------
// K1 (R1 proven form): blocks [0, SCAT): single-pass bucket scatter, each
// edge read exactly once via int4/float4 (8 independent atomic chains per
// thread; ~54 us, limiter = memory-side RMW serialization -- R2 falsified
// occupancy, R4 falsified co-scheduled-GEMM overlap).
// Blocks [SCAT, SCAT+CAST): cast input fp32 -> packed bf16 pairs.
// ---------------------------------------------------------------------------
__global__ __launch_bounds__(256) void scatter_cast(
    const int* __restrict__ row, const int* __restrict__ col,
    const float* __restrict__ vals, const float* __restrict__ input,
    int* __restrict__ cnt, unsigned* __restrict__ bucket,
    int* __restrict__ ovf_cnt, int4* __restrict__ ovf,
    unsigned* __restrict__ packed)
{
    if (blockIdx.x < SCAT_BLOCKS) {
        const int gbase = blockIdx.x * (EPB / 4);      // int4 index base
        #pragma unroll
        for (int it = 0; it < EPB / 4 / 256; ++it) {   // 2 iterations
            int gi = gbase + it * 256 + threadIdx.x;
            if (gi >= N_EDGES / 4) break;
            int4   r4 = ((const int4*)row)[gi];
            int4   c4 = ((const int4*)col)[gi];
            float4 v4 = ((const float4*)vals)[gi];
            push_edge(r4.x, c4.x, v4.x, cnt, bucket, ovf_cnt, ovf);
            push_edge(r4.y, c4.y, v4.y, cnt, bucket, ovf_cnt, ovf);
            push_edge(r4.z, c4.z, v4.z, cnt, bucket, ovf_cnt, ovf);
            push_edge(r4.w, c4.w, v4.w, cnt, bucket, ovf_cnt, ovf);
        }
    } else {
        int i = (blockIdx.x - SCAT_BLOCKS) * 256 + threadIdx.x;
        if (i >= N_NODES * D / 8) return;
        const float4* f = (const float4*)(input + (size_t)i * 8);
        float4 a = f[0], b = f[1];
        uint4 o;
        o.x = bf16rn(a.x) | (bf16rn(a.y) << 16);
        o.y = bf16rn(a.z) | (bf16rn(a.w) << 16);
        o.z = bf16rn(b.x) | (bf16rn(b.y) << 16);
        o.w = bf16rn(b.z) | (bf16rn(b.w) << 16);
        ((uint4*)packed)[i] = o;
    }
}

// ---------------------------------------------------------------------------
// K2 (FUSED gather + ovf + GEMM, 1024 threads = 16 waves, 64 rows/block).
// Fix for R3's failure: only 4 sequential rows per wave, and 2 blocks/CU x
// 16 waves = 32 resident waves/CU -- same gather parallelism as the split
// kernel, so the dependent bucket->packed chains stay hidden.
// Phase A (per wave, rows wv*4..wv*4+3): slot/q gather (~1 e-loop iter/row),
//   overflow fold (novf~0), support blend; slot-0 lanes write
//     out[g] = (1-theta)*support   (fp32 residual, exact)
//     sA[g]  = bf16(support)       (MFMA A operand)
// Phase B: W staged fp32->bf16 W^T by all 1024 threads; one barrier; MFMA
//   16 waves x (16 rows x 32 cols); epilogue out[off] += theta*acc (reads
//   this block's own L1/L2-hot lines -- pattern validated in R3, absmax ok).
// Removes: support round trip, wt prep, ovf kernel, gemm kernel (2 dispatch
// edges x ~13 us overhead measured R1/R4).
// ---------------------------------------------------------------------------
__global__ __launch_bounds__(1024) void gather_gemm(
    const unsigned* __restrict__ packed,
    const float* __restrict__ h0,
    const float* __restrict__ alpha_p,
    const int* __restrict__ cnt,
    const unsigned* __restrict__ bucket,
    const int* __restrict__ ovf_cnt_p,
    const int4* __restrict__ ovf,
    const float* __restrict__ weight,
    const float* __restrict__ lamda_p,
    const int* __restrict__ l_p,
    float* __restrict__ out)
{
    constexpr int SP = 136;                // padded LDS row stride (bf16 units)
    __shared__ ushort sA[64 * SP];         // 17,408 B
    __shared__ ushort sB[128 * SP];        // 34,816 B  (52 KB, 1024 thr -> 2/CU)

    const int tid = threadIdx.x;
    const float alpha = *alpha_p;
    const float oma = 1.0f - alpha;
    const float theta = logf((*lamda_p) / (float)(*l_p) + 1.0f);
    const float omt = 1.0f - theta;
    const int row0 = blockIdx.x * 64;

    // stage W^T: weight fp32 [k][n] -> sB bf16 [n][k]. 4096 float4, 4/thread.
    #pragma unroll
    for (int j = 0; j < 4; ++j) {
        int idx = j * 1024 + tid;
        float4 w = ((const float4*)weight)[idx];
        int k  = idx >> 5;                 // 32 float4 per k-row
        int n0 = (idx & 31) << 2;
        sB[(n0 + 0) * SP + k] = (ushort)bf16rn(w.x);
        sB[(n0 + 1) * SP + k] = (ushort)bf16rn(w.y);
        sB[(n0 + 2) * SP + k] = (ushort)bf16rn(w.z);
        sB[(n0 + 3) * SP + k] = (ushort)bf16rn(w.w);
    }

    int novf = *ovf_cnt_p;
    if (novf > OVF_CAP) novf = OVF_CAP;

    const int wv   = tid >> 6;             // 0..15
    const int lane = tid & 63;
    const int q    = lane & 15;
    const int slot = lane >> 4;
    const uint4* pk = (const uint4*)packed;           // 16 uint4 per row

    // ---- Phase A: 4 rows per wave ----
    for (int rr = 0; rr < 4; ++rr) {
        const int g = row0 + wv * 4 + rr;
        float acc[8] = {0.f, 0.f, 0.f, 0.f, 0.f, 0.f, 0.f, 0.f};

        if (g < N_NODES) {
            int n = cnt[g];
            if (n > CAP) n = CAP;
            const unsigned* b = bucket + (size_t)g * CAP;
            const int q4 = (n + 3) >> 2;              // entries per slot
            const int s0 = slot * q4;
            int s1 = s0 + q4; if (s1 > n) s1 = n;

            for (int e = s0; e < s1; e += 4) {
                int rem = s1 - e;
                unsigned m0 = b[e];
                unsigned m1 = (rem > 1) ? b[e + 1] : 0u;
                unsigned m2 = (rem > 2) ? b[e + 2] : 0u;
                unsigned m3 = (rem > 3) ? b[e + 3] : 0u;
                uint4 x0 = pk[(size_t)(m0 & 0xffffu) * 16 + q];
                uint4 x1 = pk[(size_t)(m1 & 0xffffu) * 16 + q];
                uint4 x2 = pk[(size_t)(m2 & 0xffffu) * 16 + q];
                uint4 x3 = pk[(size_t)(m3 & 0xffffu) * 16 + q];
                float v0 = (float)(m0 >> 16) * (1.0f / 1048576.0f);
                float v1 = (float)(m1 >> 16) * (1.0f / 1048576.0f);
                float v2 = (float)(m2 >> 16) * (1.0f / 1048576.0f);
                float v3 = (float)(m3 >> 16) * (1.0f / 1048576.0f);
                acc[0] += v0 * bf_lo(x0.x); acc[1] += v0 * bf_hi(x0.x);
                acc[2] += v0 * bf_lo(x0.y); acc[3] += v0 * bf_hi(x0.y);
                acc[4] += v0 * bf_lo(x0.z); acc[5] += v0 * bf_hi(x0.z);
                acc[6] += v0 * bf_lo(x0.w); acc[7] += v0 * bf_hi(x0.w);
                acc[0] += v1 * bf_lo(x1.x); acc[1] += v1 * bf_hi(x1.x);
                acc[2] += v1 * bf_lo(x1.y); acc[3] += v1 * bf_hi(x1.y);
                acc[4] += v1 * bf_lo(x1.z); acc[5] += v1 * bf_hi(x1.z);
                acc[6] += v1 * bf_lo(x1.w); acc[7] += v1 * bf_hi(x1.w);
                acc[0] += v2 * bf_lo(x2.x); acc[1] += v2 * bf_hi(x2.x);
                acc[2] += v2 * bf_lo(x2.y); acc[3] += v2 * bf_hi(x2.y);
                acc[4] += v2 * bf_lo(x2.z); acc[5] += v2 * bf_hi(x2.z);
                acc[6] += v2 * bf_lo(x2.w); acc[7] += v2 * bf_hi(x2.w);
                acc[0] += v3 * bf_lo(x3.x); acc[1] += v3 * bf_hi(x3.x);
                acc[2] += v3 * bf_lo(x3.y); acc[3] += v3 * bf_hi(x3.y);
                acc[4] += v3 * bf_lo(x3.z); acc[5] += v3 * bf_hi(x3.z);
                acc[6] += v3 * bf_lo(x3.w); acc[7] += v3 * bf_hi(x3.w);
            }
        }
        #pragma unroll
        for (int j = 0; j < 8; ++j) {
            acc[j] += __shfl_xor(acc[j], 16);
            acc[j] += __shfl_xor(acc[j], 32);
        }
        if (slot == 0) {                              // lanes 0..15
            uint4 pkv = make_uint4(0, 0, 0, 0);
            if (g < N_NODES) {
                for (int o = 0; o < novf; ++o) {      // fold overflow (novf~0)
                    int4 mm = ovf[o];
                    if (mm.x == g) {
                        float v = __int_as_float(mm.z);
                        uint4 x = pk[(size_t)mm.y * 16 + q];
                        acc[0] += v * bf_lo(x.x); acc[1] += v * bf_hi(x.x);
                        acc[2] += v * bf_lo(x.y); acc[3] += v * bf_hi(x.y);
                        acc[4] += v * bf_lo(x.z); acc[5] += v * bf_hi(x.z);
                        acc[6] += v * bf_lo(x.w); acc[7] += v * bf_hi(x.w);
                    }
                }
                const float* hp = h0 + (size_t)g * D + q * 8;
                float4 ha = *(const float4*)(hp);
                float4 hb = *(const float4*)(hp + 4);
                float s0 = oma * acc[0] + alpha * ha.x;
                float s1 = oma * acc[1] + alpha * ha.y;
                float s2 = oma * acc[2] + alpha * ha.z;
                float s3 = oma * acc[3] + alpha * ha.w;
                float s4 = oma * acc[4] + alpha * hb.x;
                float s5 = oma * acc[5] + alpha * hb.y;
                float s6 = oma * acc[6] + alpha * hb.z;
                float s7 = oma * acc[7] + alpha * hb.w;
                float* op = out + (size_t)g * D + q * 8;
                *(float4*)(op)     = make_float4(omt * s0, omt * s1, omt * s2, omt * s3);
                *(float4*)(op + 4) = make_float4(omt * s4, omt * s5, omt * s6, omt * s7);
                pkv.x = bf16rn(s0) | (bf16rn(s1) << 16);
                pkv.y = bf16rn(s2) | (bf16rn(s3) << 16);
                pkv.z = bf16rn(s4) | (bf16rn(s5) << 16);
                pkv.w = bf16rn(s6) | (bf16rn(s7) << 16);
            }
            *(uint4*)(&sA[(wv * 4 + rr) * SP + q * 8]) = pkv;
        }
    }
    __syncthreads();

    // ---- Phase B: MFMA. 16 waves: wr = wv&3 (16-row group), wc = wv>>2
    // (32-col group). Each wave: 2 N-tiles x 4 K-blocks.
    const int m    = lane & 15;
    const int quad = lane >> 4;
    const int wr   = wv & 3;
    const int wc   = wv >> 2;
    const int arow = wr * 16 + m;

    f32x4 acc2[2] = {};
    #pragma unroll
    for (int kb = 0; kb < 4; ++kb) {
        bf16x8 a = *(const bf16x8*)(&sA[arow * SP + kb * 32 + quad * 8]);
        #pragma unroll
        for (int nt = 0; nt < 2; ++nt) {
            bf16x8 b = *(const bf16x8*)(&sB[(wc * 32 + nt * 16 + m) * SP + kb * 32 + quad * 8]);
            acc2[nt] = __builtin_amdgcn_mfma_f32_16x16x32_bf16(a, b, acc2[nt], 0, 0, 0);
        }
    }

    // epilogue: out[off] += theta * acc (out holds (1-theta)*support, L2-hot)
    const int gbase = row0 + wr * 16 + quad * 4;
    #pragma unroll
    for (int nt = 0; nt < 2; ++nt) {
        int c = wc * 32 + nt * 16 + m;
        #pragma unroll
        for (int i = 0; i < 4; ++i) {
            int g = gbase + i;
            if (g < N_NODES) {
                size_t off = (size_t)g * D + c;
                out[off] = out[off] + theta * acc2[nt][i];
            }
        }
    }
}

extern "C" void kernel_launch(void* const* d_in, const int* in_sizes, int n_in,
                              void* d_out, int out_size, void* d_ws, size_t ws_size,
                              hipStream_t stream) {
    const float* input  = (const float*)d_in[0];
    const float* h0     = (const float*)d_in[1];
    const float* vals   = (const float*)d_in[2];
    const float* weight = (const float*)d_in[3];
    const float* lamda  = (const float*)d_in[4];
    const float* alpha  = (const float*)d_in[5];
    const int*   row    = (const int*)d_in[6];
    const int*   col    = (const int*)d_in[7];
    const int*   l      = (const int*)d_in[8];
    float* out = (float*)d_out;

    char* ws = (char*)d_ws;
    int*      cnt     = (int*)ws;
    int*      ovf_cnt = (int*)(ws + OFF_OVFCNT);
    unsigned* bucket  = (unsigned*)(ws + OFF_BUCKET);
    int4*     ovf     = (int4*)(ws + OFF_OVF);
    unsigned* packed  = (unsigned*)(ws + OFF_PACKED);

    // zero cnt + ovf_cnt only (ws is re-poisoned to 0xAA before every launch)
    hipMemsetAsync(ws, 0, OFF_BUCKET, stream);

    scatter_cast<<<SCAT_BLOCKS + CAST_BLOCKS, 256, 0, stream>>>(
        row, col, vals, input, cnt, bucket, ovf_cnt, ovf, packed);

    int fusedb = (N_NODES + 63) / 64;                // 782 blocks x 1024 thr
    gather_gemm<<<fusedb, 1024, 0, stream>>>(
        packed, h0, alpha, cnt, bucket, ovf_cnt, ovf, weight, lamda, l, out);
}

// Round 6
// 204.568 us; speedup vs baseline: 1.1208x; 1.1208x over previous
//
#include <hip/hip_runtime.h>
#include <cmath>

constexpr int N_NODES = 50000;
constexpr int N_EDGES = 800000;
constexpr int D = 128;
constexpr int CAP = 32;           // bucket capacity (Poisson(16); ovf fallback)
constexpr int OVF_CAP = 8192;
constexpr int CNT_STRIDE = 16;    // one counter per 64B line (anti-contention)

constexpr int EPB = 2048;                                  // edges per scatter block
constexpr int SCAT_BLOCKS = (N_EDGES + EPB - 1) / EPB;     // 391 (single pass)
constexpr int CAST_BLOCKS = (N_NODES * D / 8 + 255) / 256; // 3125 (uint4/thread)
// + 1 block converting W -> bf16 W^T

// ---- workspace layout (bytes) ----
// cnt     : int[N_NODES*16]     @ 0            (3,200,000)  (stride-16 padded)
// ovf_cnt : int                 @ 3,200,000
// bucket  : uint[N_NODES*CAP]   @ 3,200,064    (6,400,000)
// ovf     : int4[OVF_CAP]       @ 9,600,064    (131,072)
// packed  : uint[N_NODES*D/2]   @ 9,731,136    (12,800,000)
// wt      : ushort[D*D]         @ 22,531,136   (32,768) -> end 22,563,904
constexpr size_t OFF_OVFCNT = 3200000;
constexpr size_t OFF_BUCKET = 3200064;
constexpr size_t OFF_OVF    = 9600064;
constexpr size_t OFF_PACKED = 9731136;
constexpr size_t OFF_WT     = 22531136;

typedef __attribute__((ext_vector_type(8))) short bf16x8;
typedef __attribute__((ext_vector_type(4))) float f32x4;

__device__ __forceinline__ unsigned bf16rn(float f) {
    unsigned u = __float_as_uint(f);
    return (u + 0x7fffu + ((u >> 16) & 1u)) >> 16;   // round-to-nearest-even
}
__device__ __forceinline__ float bf_lo(unsigned u) { return __uint_as_float(u << 16); }
__device__ __forceinline__ float bf_hi(unsigned u) { return __uint_as_float(u & 0xffff0000u); }

// val in [0, 1/16) -> 16-bit fixed point (x 2^20). quant step 2^-20.
__device__ __forceinline__ unsigned enc_val(float v) {
    int m = (int)(v * 1048576.0f + 0.5f);
    if (m > 65535) m = 65535;
    if (m < 0) m = 0;
    return (unsigned)m;
}

__device__ __forceinline__ void push_edge(
    int r, int c, float v,
    int* __restrict__ cnt, unsigned* __restrict__ bucket,
    int* __restrict__ ovf_cnt, int4* __restrict__ ovf)
{
    unsigned ent = (unsigned)c | (enc_val(v) << 16);
    int pos = atomicAdd(&cnt[(size_t)r * CNT_STRIDE], 1);
    if (pos < CAP) bucket[(size_t)r * CAP + pos] = ent;
    else {
        int o = atomicAdd(ovf_cnt, 1);
        if (o < OVF_CAP) ovf[o] = make_int4(r, c, __float_as_int(v), 0);
    }
}

// ---------------------------------------------------------------------------
// K1 (R1 proven form + padded cnt): blocks [0, SCAT): single-pass bucket
// scatter, each edge read exactly once via int4/float4 (8 independent atomic
// chains/thread). cnt padded to 1 counter per 64B line: tests whether the
// ~54 us scatter floor was memory-side LINE-level RMW serialization (256
// atomics/line unpadded -> 16/line padded).
// Blocks [SCAT, SCAT+CAST): cast input fp32 -> packed bf16 pairs.
// Last block: W fp32 -> bf16 W^T (consumed by K3's conflict-free staging).
// ---------------------------------------------------------------------------
__global__ __launch_bounds__(256) void scatter_cast(
    const int* __restrict__ row, const int* __restrict__ col,
    const float* __restrict__ vals, const float* __restrict__ input,
    const float* __restrict__ weight,
    int* __restrict__ cnt, unsigned* __restrict__ bucket,
    int* __restrict__ ovf_cnt, int4* __restrict__ ovf,
    unsigned* __restrict__ packed, ushort* __restrict__ wt)
{
    if (blockIdx.x < SCAT_BLOCKS) {
        const int gbase = blockIdx.x * (EPB / 4);      // int4 index base
        #pragma unroll
        for (int it = 0; it < EPB / 4 / 256; ++it) {   // 2 iterations
            int gi = gbase + it * 256 + threadIdx.x;
            if (gi >= N_EDGES / 4) break;
            int4   r4 = ((const int4*)row)[gi];
            int4   c4 = ((const int4*)col)[gi];
            float4 v4 = ((const float4*)vals)[gi];
            push_edge(r4.x, c4.x, v4.x, cnt, bucket, ovf_cnt, ovf);
            push_edge(r4.y, c4.y, v4.y, cnt, bucket, ovf_cnt, ovf);
            push_edge(r4.z, c4.z, v4.z, cnt, bucket, ovf_cnt, ovf);
            push_edge(r4.w, c4.w, v4.w, cnt, bucket, ovf_cnt, ovf);
        }
    } else if (blockIdx.x < SCAT_BLOCKS + CAST_BLOCKS) {
        int i = (blockIdx.x - SCAT_BLOCKS) * 256 + threadIdx.x;
        if (i >= N_NODES * D / 8) return;
        const float4* f = (const float4*)(input + (size_t)i * 8);
        float4 a = f[0], b = f[1];
        uint4 o;
        o.x = bf16rn(a.x) | (bf16rn(a.y) << 16);
        o.y = bf16rn(a.z) | (bf16rn(a.w) << 16);
        o.z = bf16rn(b.x) | (bf16rn(b.y) << 16);
        o.w = bf16rn(b.z) | (bf16rn(b.w) << 16);
        ((uint4*)packed)[i] = o;
    } else {
        // W (row-major [k][n]) -> wt bf16 [n][k]; 16384 elems, 64/thread.
        #pragma unroll
        for (int j = 0; j < 64; ++j) {
            int idx = threadIdx.x + j * 256;
            int k = idx >> 7, n = idx & 127;
            wt[n * 128 + k] = (ushort)bf16rn(weight[idx]);
        }
    }
}

// ---------------------------------------------------------------------------
// K2: pull-gather (bf16 operand) + overflow fold + support blend.
// One wave per row (R1 proven shape; R3/R5 falsified row-batching/fusion).
// Lanes: q = lane&15 (16B chunk of the row), slot = lane>>4; slot h owns a
// contiguous quarter of the entries; 4 independent row fetches in flight.
// Writes support (fp32) into d_out; K3 consumes it in place.
// ---------------------------------------------------------------------------
__global__ __launch_bounds__(256) void gather_support(
    const unsigned* __restrict__ packed,
    const float* __restrict__ h0,
    const float* __restrict__ alpha_p,
    const int* __restrict__ cnt,
    const unsigned* __restrict__ bucket,
    const int* __restrict__ ovf_cnt_p,
    const int4* __restrict__ ovf,
    float* __restrict__ support)
{
    const float alpha = *alpha_p;
    const float oma = 1.0f - alpha;
    const int wv   = threadIdx.x >> 6;
    const int lane = threadIdx.x & 63;
    const int q    = lane & 15;
    const int slot = lane >> 4;

    const int g = blockIdx.x * 4 + wv;
    if (g >= N_NODES) return;

    int n = cnt[(size_t)g * CNT_STRIDE];
    int novf = *ovf_cnt_p;
    if (novf > OVF_CAP) novf = OVF_CAP;
    if (n > CAP) n = CAP;
    const unsigned* b = bucket + (size_t)g * CAP;
    const uint4* pk = (const uint4*)packed;           // 16 uint4 per row

    const int q4 = (n + 3) >> 2;                      // entries per slot
    const int s0 = slot * q4;
    int s1 = s0 + q4; if (s1 > n) s1 = n;

    float acc[8] = {0.f, 0.f, 0.f, 0.f, 0.f, 0.f, 0.f, 0.f};
    for (int e = s0; e < s1; e += 4) {
        int rem = s1 - e;
        unsigned m0 = b[e];
        unsigned m1 = (rem > 1) ? b[e + 1] : 0u;
        unsigned m2 = (rem > 2) ? b[e + 2] : 0u;
        unsigned m3 = (rem > 3) ? b[e + 3] : 0u;
        uint4 x0 = pk[(size_t)(m0 & 0xffffu) * 16 + q];
        uint4 x1 = pk[(size_t)(m1 & 0xffffu) * 16 + q];
        uint4 x2 = pk[(size_t)(m2 & 0xffffu) * 16 + q];
        uint4 x3 = pk[(size_t)(m3 & 0xffffu) * 16 + q];
        float v0 = (float)(m0 >> 16) * (1.0f / 1048576.0f);
        float v1 = (float)(m1 >> 16) * (1.0f / 1048576.0f);
        float v2 = (float)(m2 >> 16) * (1.0f / 1048576.0f);
        float v3 = (float)(m3 >> 16) * (1.0f / 1048576.0f);
        acc[0] += v0 * bf_lo(x0.x); acc[1] += v0 * bf_hi(x0.x);
        acc[2] += v0 * bf_lo(x0.y); acc[3] += v0 * bf_hi(x0.y);
        acc[4] += v0 * bf_lo(x0.z); acc[5] += v0 * bf_hi(x0.z);
        acc[6] += v0 * bf_lo(x0.w); acc[7] += v0 * bf_hi(x0.w);
        acc[0] += v1 * bf_lo(x1.x); acc[1] += v1 * bf_hi(x1.x);
        acc[2] += v1 * bf_lo(x1.y); acc[3] += v1 * bf_hi(x1.y);
        acc[4] += v1 * bf_lo(x1.z); acc[5] += v1 * bf_hi(x1.z);
        acc[6] += v1 * bf_lo(x1.w); acc[7] += v1 * bf_hi(x1.w);
        acc[0] += v2 * bf_lo(x2.x); acc[1] += v2 * bf_hi(x2.x);
        acc[2] += v2 * bf_lo(x2.y); acc[3] += v2 * bf_hi(x2.y);
        acc[4] += v2 * bf_lo(x2.z); acc[5] += v2 * bf_hi(x2.z);
        acc[6] += v2 * bf_lo(x2.w); acc[7] += v2 * bf_hi(x2.w);
        acc[0] += v3 * bf_lo(x3.x); acc[1] += v3 * bf_hi(x3.x);
        acc[2] += v3 * bf_lo(x3.y); acc[3] += v3 * bf_hi(x3.y);
        acc[4] += v3 * bf_lo(x3.z); acc[5] += v3 * bf_hi(x3.z);
        acc[6] += v3 * bf_lo(x3.w); acc[7] += v3 * bf_hi(x3.w);
    }
    #pragma unroll
    for (int j = 0; j < 8; ++j) {
        acc[j] += __shfl_xor(acc[j], 16);
        acc[j] += __shfl_xor(acc[j], 32);
    }
    if (slot == 0) {                                  // lanes 0..15
        // fold overflow edges for this row (novf ~ 0; safety net)
        for (int o = 0; o < novf; ++o) {
            int4 mm = ovf[o];
            if (mm.x == g) {
                float v = __int_as_float(mm.z);
                uint4 x = pk[(size_t)mm.y * 16 + q];
                acc[0] += v * bf_lo(x.x); acc[1] += v * bf_hi(x.x);
                acc[2] += v * bf_lo(x.y); acc[3] += v * bf_hi(x.y);
                acc[4] += v * bf_lo(x.z); acc[5] += v * bf_hi(x.z);
                acc[6] += v * bf_lo(x.w); acc[7] += v * bf_hi(x.w);
            }
        }
        const float* hp = h0 + (size_t)g * D + q * 8;
        float4 ha = *(const float4*)(hp);
        float4 hb = *(const float4*)(hp + 4);
        float* sp = support + (size_t)g * D + q * 8;
        float4 sa, sb;
        sa.x = oma * acc[0] + alpha * ha.x;
        sa.y = oma * acc[1] + alpha * ha.y;
        sa.z = oma * acc[2] + alpha * ha.z;
        sa.w = oma * acc[3] + alpha * ha.w;
        sb.x = oma * acc[4] + alpha * hb.x;
        sb.y = oma * acc[5] + alpha * hb.y;
        sb.z = oma * acc[6] + alpha * hb.z;
        sb.w = oma * acc[7] + alpha * hb.w;
        *(float4*)(sp) = sa;
        *(float4*)(sp + 4) = sb;
    }
}

// ---------------------------------------------------------------------------
// K3: MFMA bf16 in-place GEMM + epilogue on d_out (R1 proven form).
//   data[r] (out) = theta * bf16(data[r]) @ bf16(W) + (1-theta) * data[r]
// LDS: sA 64x136 bf16 + sB (W^T) 128x136 bf16 = 52 KB -> 3 blocks/CU.
// ---------------------------------------------------------------------------
__global__ __launch_bounds__(256) void gemm_mfma(
    const ushort* __restrict__ wt,
    const float* __restrict__ lamda_p,
    const int* __restrict__ l_p,
    float* __restrict__ data)
{
    constexpr int SP = 136;                // padded LDS row stride (bf16 units)
    __shared__ ushort sA[64 * SP];         // 17,408 B
    __shared__ ushort sB[128 * SP];        // 34,816 B

    const int tid = threadIdx.x;
    const float lamda = *lamda_p;
    const float theta = logf(lamda / (float)(*l_p) + 1.0f);
    const float omt = 1.0f - theta;
    const int row0 = blockIdx.x * 64;

    // stage W^T: 2048 uint4 (8 bf16 each) over 256 threads -> 8 each
    #pragma unroll
    for (int j = 0; j < 8; ++j) {
        int idx = j * 256 + tid;
        int n  = idx >> 4;
        int k8 = (idx & 15) << 3;
        *(uint4*)(&sB[n * SP + k8]) = ((const uint4*)wt)[idx];
    }
    // stage A tile: support fp32 -> bf16. 2048 float4 groups -> 8 each.
    #pragma unroll
    for (int j = 0; j < 8; ++j) {
        int idx = j * 256 + tid;
        int rr = idx >> 5;
        int c4 = (idx & 31) << 2;
        int g = row0 + rr;
        float4 s = make_float4(0.f, 0.f, 0.f, 0.f);
        if (g < N_NODES) s = *(const float4*)(data + (size_t)g * D + c4);
        uint2 pkv;
        pkv.x = bf16rn(s.x) | (bf16rn(s.y) << 16);
        pkv.y = bf16rn(s.z) | (bf16rn(s.w) << 16);
        *(uint2*)(&sA[rr * SP + c4]) = pkv;
    }
    __syncthreads();

    const int wave = tid >> 6;
    const int lane = tid & 63;
    const int m    = lane & 15;
    const int quad = lane >> 4;
    const int arow = wave * 16 + m;

    f32x4 acc[8] = {};                      // 8 N-tiles of 16 cols
    #pragma unroll
    for (int kb = 0; kb < 4; ++kb) {
        bf16x8 a = *(const bf16x8*)(&sA[arow * SP + kb * 32 + quad * 8]);
        #pragma unroll
        for (int nt = 0; nt < 8; ++nt) {
            bf16x8 b = *(const bf16x8*)(&sB[(nt * 16 + m) * SP + kb * 32 + quad * 8]);
            acc[nt] = __builtin_amdgcn_mfma_f32_16x16x32_bf16(a, b, acc[nt], 0, 0, 0);
        }
    }

    // epilogue: rows row0 + wave*16 + quad*4 + i, col nt*16 + m
    const int gbase = row0 + wave * 16 + quad * 4;
    #pragma unroll
    for (int nt = 0; nt < 8; ++nt) {
        int colb = nt * 16 + m;
        #pragma unroll
        for (int i = 0; i < 4; ++i) {
            int g = gbase + i;
            if (g < N_NODES) {
                size_t off = (size_t)g * D + colb;
                float s = data[off];
                data[off] = theta * acc[nt][i] + omt * s;
            }
        }
    }
}

extern "C" void kernel_launch(void* const* d_in, const int* in_sizes, int n_in,
                              void* d_out, int out_size, void* d_ws, size_t ws_size,
                              hipStream_t stream) {
    const float* input  = (const float*)d_in[0];
    const float* h0     = (const float*)d_in[1];
    const float* vals   = (const float*)d_in[2];
    const float* weight = (const float*)d_in[3];
    const float* lamda  = (const float*)d_in[4];
    const float* alpha  = (const float*)d_in[5];
    const int*   row    = (const int*)d_in[6];
    const int*   col    = (const int*)d_in[7];
    const int*   l      = (const int*)d_in[8];
    float* out = (float*)d_out;

    char* ws = (char*)d_ws;
    int*      cnt     = (int*)ws;
    int*      ovf_cnt = (int*)(ws + OFF_OVFCNT);
    unsigned* bucket  = (unsigned*)(ws + OFF_BUCKET);
    int4*     ovf     = (int4*)(ws + OFF_OVF);
    unsigned* packed  = (unsigned*)(ws + OFF_PACKED);
    ushort*   wt      = (ushort*)(ws + OFF_WT);

    // zero cnt (padded, 3.2MB) + ovf_cnt (ws is re-poisoned before launches)
    hipMemsetAsync(ws, 0, OFF_BUCKET, stream);

    scatter_cast<<<SCAT_BLOCKS + CAST_BLOCKS + 1, 256, 0, stream>>>(
        row, col, vals, input, weight, cnt, bucket, ovf_cnt, ovf, packed, wt);

    int gatherb = (N_NODES + 3) / 4;                 // 12500 (4 waves/block)
    gather_support<<<gatherb, 256, 0, stream>>>(
        packed, h0, alpha, cnt, bucket, ovf_cnt, ovf, out);

    int gemmb = (N_NODES + 63) / 64;                 // 782
    gemm_mfma<<<gemmb, 256, 0, stream>>>(wt, lamda, l, out);
}

// Round 7
// 188.683 us; speedup vs baseline: 1.2151x; 1.0842x over previous
//
#include <hip/hip_runtime.h>
#include <cmath>

constexpr int N_NODES = 50000;
constexpr int N_EDGES = 800000;
constexpr int D = 128;
constexpr int CAP = 32;           // bucket capacity (Poisson(16); ovf fallback)
constexpr int OVF_CAP = 8192;

// ---- two-phase binned scatter ----
constexpr int NBIN = 256;                      // row partitions
constexpr int RPP  = 196;                      // rows/partition (256*196=50176)
constexpr int QCAP = 4096;                     // entries/queue (mean 3125, +17 sigma)
constexpr int QCNT_STRIDE = 16;                // one qcnt per 64B line
constexpr int EPB_BIN = 4096;                  // edges per bin block
constexpr int BIN_BLOCKS = (N_EDGES + EPB_BIN - 1) / EPB_BIN;   // 196
constexpr int CAST_BLOCKS = (N_NODES * D / 8 + 255) / 256;      // 3125
// K1 grid = BIN_BLOCKS + CAST_BLOCKS + 1 (W^T)

// ---- workspace layout (bytes) ----
// qcnt    : int[NBIN*16]        @ 0            (16,384)
// ovf_cnt : int                 @ 16,384
// queue   : uint2[NBIN*QCAP]    @ 16,448       (8,388,608)
// cnt     : int[N_NODES]        @ 8,405,056    (200,000)
// bucket  : uint[N_NODES*CAP]   @ 8,605,056    (6,400,000)
// ovf     : int4[OVF_CAP]       @ 15,005,056   (131,072)
// packed  : uint[N_NODES*D/2]   @ 15,136,128   (12,800,000)
// wt      : ushort[D*D]         @ 27,936,128   (32,768) -> end 27,968,896
constexpr size_t OFF_OVFCNT = 16384;
constexpr size_t OFF_QUEUE  = 16448;
constexpr size_t OFF_CNT    = 8405056;
constexpr size_t OFF_BUCKET = 8605056;
constexpr size_t OFF_OVF    = 15005056;
constexpr size_t OFF_PACKED = 15136128;
constexpr size_t OFF_WT     = 27936128;

typedef __attribute__((ext_vector_type(8))) short bf16x8;
typedef __attribute__((ext_vector_type(4))) float f32x4;

__device__ __forceinline__ unsigned bf16rn(float f) {
    unsigned u = __float_as_uint(f);
    return (u + 0x7fffu + ((u >> 16) & 1u)) >> 16;   // round-to-nearest-even
}
__device__ __forceinline__ float bf_lo(unsigned u) { return __uint_as_float(u << 16); }
__device__ __forceinline__ float bf_hi(unsigned u) { return __uint_as_float(u & 0xffff0000u); }

// val in [0, 1/16) -> 16-bit fixed point (x 2^20). quant step 2^-20.
__device__ __forceinline__ unsigned enc_val(float v) {
    int m = (int)(v * 1048576.0f + 0.5f);
    if (m > 65535) m = 65535;
    if (m < 0) m = 0;
    return (unsigned)m;
}

// ---------------------------------------------------------------------------
// K1: blocks [0, BIN_BLOCKS): LDS counting-sort of 4096 edges into 256
// row-partitions, then CONTIGUOUS per-bin append to global queues (256
// global atomics/block vs 4096 -- 16x fewer; appends are ~128B chunks).
// Rationale: R1/R6 scatter wrote 60 MB = one full line writeback PER 4B
// bucket entry (cross-XCD line ping-pong). Queues make all heavy traffic
// coalesced; bucket lines are written once, by K2.
// Blocks [BIN, BIN+CAST): cast input fp32 -> packed bf16. Last: W -> W^T.
// ---------------------------------------------------------------------------
__global__ __launch_bounds__(256) void binsort_cast(
    const int* __restrict__ row, const int* __restrict__ col,
    const float* __restrict__ vals, const float* __restrict__ input,
    const float* __restrict__ weight,
    int* __restrict__ qcnt, uint2* __restrict__ queue,
    int* __restrict__ ovf_cnt, int4* __restrict__ ovf,
    unsigned* __restrict__ packed, ushort* __restrict__ wt)
{
    __shared__ uint2 lq[EPB_BIN];              // 32 KB bin-sorted staging
    __shared__ int hist[NBIN], scn[NBIN], off[NBIN], gbase[NBIN], fill[NBIN];

    const int tid = threadIdx.x;
    if (blockIdx.x < BIN_BLOCKS) {
        int er[16]; unsigned ec[16];
        const int gi0 = blockIdx.x * (EPB_BIN / 4);
        #pragma unroll
        for (int it = 0; it < 4; ++it) {
            int gi = gi0 + it * 256 + tid;
            int4 r4 = make_int4(-1, -1, -1, -1);
            int4 c4 = make_int4(0, 0, 0, 0);
            float4 v4 = make_float4(0.f, 0.f, 0.f, 0.f);
            if (gi < N_EDGES / 4) {
                r4 = ((const int4*)row)[gi];
                c4 = ((const int4*)col)[gi];
                v4 = ((const float4*)vals)[gi];
            }
            er[it*4+0] = r4.x; ec[it*4+0] = (unsigned)c4.x | (enc_val(v4.x) << 16);
            er[it*4+1] = r4.y; ec[it*4+1] = (unsigned)c4.y | (enc_val(v4.y) << 16);
            er[it*4+2] = r4.z; ec[it*4+2] = (unsigned)c4.z | (enc_val(v4.z) << 16);
            er[it*4+3] = r4.w; ec[it*4+3] = (unsigned)c4.w | (enc_val(v4.w) << 16);
        }
        hist[tid] = 0;
        __syncthreads();
        #pragma unroll
        for (int j = 0; j < 16; ++j)
            if (er[j] >= 0) atomicAdd(&hist[er[j] / RPP], 1);
        __syncthreads();
        // inclusive Hillis-Steele scan over 256 bins
        scn[tid] = hist[tid];
        __syncthreads();
        for (int s = 1; s < NBIN; s <<= 1) {
            int t = (tid >= s) ? scn[tid - s] : 0;
            __syncthreads();
            scn[tid] += t;
            __syncthreads();
        }
        off[tid]   = scn[tid] - hist[tid];     // exclusive offset
        gbase[tid] = atomicAdd(&qcnt[tid * QCNT_STRIDE], hist[tid]);
        fill[tid]  = 0;
        __syncthreads();
        #pragma unroll
        for (int j = 0; j < 16; ++j)
            if (er[j] >= 0) {
                int b = er[j] / RPP;
                int p = atomicAdd(&fill[b], 1);
                lq[off[b] + p] = make_uint2(ec[j], (unsigned)er[j]);
            }
        __syncthreads();
        const int total = scn[NBIN - 1];
        for (int i = tid; i < total; i += 256) {
            uint2 e = lq[i];
            int r = (int)e.y;
            int b = r / RPP;
            int dst = gbase[b] + (i - off[b]);
            if (dst < QCAP) queue[(size_t)b * QCAP + dst] = e;
            else {                             // queue overflow (17-sigma; safety)
                int o = atomicAdd(ovf_cnt, 1);
                if (o < OVF_CAP) ovf[o] = make_int4(r, (int)(e.x & 0xffffu),
                    __float_as_int((float)(e.x >> 16) * (1.0f / 1048576.0f)), 0);
            }
        }
    } else if (blockIdx.x < BIN_BLOCKS + CAST_BLOCKS) {
        int i = (blockIdx.x - BIN_BLOCKS) * 256 + tid;
        if (i >= N_NODES * D / 8) return;
        const float4* f = (const float4*)(input + (size_t)i * 8);
        float4 a = f[0], b = f[1];
        uint4 o;
        o.x = bf16rn(a.x) | (bf16rn(a.y) << 16);
        o.y = bf16rn(a.z) | (bf16rn(a.w) << 16);
        o.z = bf16rn(b.x) | (bf16rn(b.y) << 16);
        o.w = bf16rn(b.z) | (bf16rn(b.w) << 16);
        ((uint4*)packed)[i] = o;
    } else {
        // W (row-major [k][n]) -> wt bf16 [n][k]; 16384 elems, 64/thread.
        #pragma unroll
        for (int j = 0; j < 64; ++j) {
            int idx = tid + j * 256;
            int k = idx >> 7, n = idx & 127;
            wt[n * 128 + k] = (ushort)bf16rn(weight[idx]);
        }
    }
}

// ---------------------------------------------------------------------------
// K2: drain. One block per partition owns 196 rows EXCLUSIVELY: builds
// cnt+bucket in LDS (LDS atomics only, no global atomics), writes both out
// fully coalesced (each bucket line written exactly once: ~6.6 MB total vs
// the old 60 MB scattered writeback).
// ---------------------------------------------------------------------------
__global__ __launch_bounds__(256) void bucket_build(
    const uint2* __restrict__ queue, const int* __restrict__ qcnt,
    int* __restrict__ ovf_cnt, int4* __restrict__ ovf,
    int* __restrict__ cnt, unsigned* __restrict__ bucket)
{
    __shared__ int cl[RPP];                    // per-row counts
    __shared__ unsigned lb[RPP * CAP];         // 25,088 B local buckets

    const int b = blockIdx.x;
    const int tid = threadIdx.x;
    if (tid < RPP) cl[tid] = 0;
    __syncthreads();

    int nb = qcnt[b * QCNT_STRIDE];
    if (nb > QCAP) nb = QCAP;
    for (int i = tid; i < nb; i += 256) {
        uint2 e = queue[(size_t)b * QCAP + i];
        int r  = (int)e.y;
        int rl = r - b * RPP;
        int pos = atomicAdd(&cl[rl], 1);
        if (pos < CAP) lb[rl * CAP + pos] = e.x;
        else {
            int o = atomicAdd(ovf_cnt, 1);
            if (o < OVF_CAP) ovf[o] = make_int4(r, (int)(e.x & 0xffffu),
                __float_as_int((float)(e.x >> 16) * (1.0f / 1048576.0f)), 0);
        }
    }
    __syncthreads();

    if (tid < RPP) {
        int r = b * RPP + tid;
        if (r < N_NODES) cnt[r] = cl[tid];
    }
    for (int i = tid; i < RPP * CAP; i += 256) {
        int gidx = b * RPP * CAP + i;
        if (gidx < N_NODES * CAP) bucket[gidx] = lb[i];
    }
}

// ---------------------------------------------------------------------------
// K3: pull-gather (bf16 operand) + overflow fold + support blend.
// One wave per row (R1 proven shape; R3/R5 falsified row-batching/fusion).
// Writes support (fp32) into d_out; K4 consumes it in place.
// ---------------------------------------------------------------------------
__global__ __launch_bounds__(256) void gather_support(
    const unsigned* __restrict__ packed,
    const float* __restrict__ h0,
    const float* __restrict__ alpha_p,
    const int* __restrict__ cnt,
    const unsigned* __restrict__ bucket,
    const int* __restrict__ ovf_cnt_p,
    const int4* __restrict__ ovf,
    float* __restrict__ support)
{
    const float alpha = *alpha_p;
    const float oma = 1.0f - alpha;
    const int wv   = threadIdx.x >> 6;
    const int lane = threadIdx.x & 63;
    const int q    = lane & 15;
    const int slot = lane >> 4;

    const int g = blockIdx.x * 4 + wv;
    if (g >= N_NODES) return;

    int n = cnt[g];
    int novf = *ovf_cnt_p;
    if (novf > OVF_CAP) novf = OVF_CAP;
    if (n > CAP) n = CAP;
    const unsigned* b = bucket + (size_t)g * CAP;
    const uint4* pk = (const uint4*)packed;           // 16 uint4 per row

    const int q4 = (n + 3) >> 2;                      // entries per slot
    const int s0 = slot * q4;
    int s1 = s0 + q4; if (s1 > n) s1 = n;

    float acc[8] = {0.f, 0.f, 0.f, 0.f, 0.f, 0.f, 0.f, 0.f};
    for (int e = s0; e < s1; e += 4) {
        int rem = s1 - e;
        unsigned m0 = b[e];
        unsigned m1 = (rem > 1) ? b[e + 1] : 0u;
        unsigned m2 = (rem > 2) ? b[e + 2] : 0u;
        unsigned m3 = (rem > 3) ? b[e + 3] : 0u;
        uint4 x0 = pk[(size_t)(m0 & 0xffffu) * 16 + q];
        uint4 x1 = pk[(size_t)(m1 & 0xffffu) * 16 + q];
        uint4 x2 = pk[(size_t)(m2 & 0xffffu) * 16 + q];
        uint4 x3 = pk[(size_t)(m3 & 0xffffu) * 16 + q];
        float v0 = (float)(m0 >> 16) * (1.0f / 1048576.0f);
        float v1 = (float)(m1 >> 16) * (1.0f / 1048576.0f);
        float v2 = (float)(m2 >> 16) * (1.0f / 1048576.0f);
        float v3 = (float)(m3 >> 16) * (1.0f / 1048576.0f);
        acc[0] += v0 * bf_lo(x0.x); acc[1] += v0 * bf_hi(x0.x);
        acc[2] += v0 * bf_lo(x0.y); acc[3] += v0 * bf_hi(x0.y);
        acc[4] += v0 * bf_lo(x0.z); acc[5] += v0 * bf_hi(x0.z);
        acc[6] += v0 * bf_lo(x0.w); acc[7] += v0 * bf_hi(x0.w);
        acc[0] += v1 * bf_lo(x1.x); acc[1] += v1 * bf_hi(x1.x);
        acc[2] += v1 * bf_lo(x1.y); acc[3] += v1 * bf_hi(x1.y);
        acc[4] += v1 * bf_lo(x1.z); acc[5] += v1 * bf_hi(x1.z);
        acc[6] += v1 * bf_lo(x1.w); acc[7] += v1 * bf_hi(x1.w);
        acc[0] += v2 * bf_lo(x2.x); acc[1] += v2 * bf_hi(x2.x);
        acc[2] += v2 * bf_lo(x2.y); acc[3] += v2 * bf_hi(x2.y);
        acc[4] += v2 * bf_lo(x2.z); acc[5] += v2 * bf_hi(x2.z);
        acc[6] += v2 * bf_lo(x2.w); acc[7] += v2 * bf_hi(x2.w);
        acc[0] += v3 * bf_lo(x3.x); acc[1] += v3 * bf_hi(x3.x);
        acc[2] += v3 * bf_lo(x3.y); acc[3] += v3 * bf_hi(x3.y);
        acc[4] += v3 * bf_lo(x3.z); acc[5] += v3 * bf_hi(x3.z);
        acc[6] += v3 * bf_lo(x3.w); acc[7] += v3 * bf_hi(x3.w);
    }
    #pragma unroll
    for (int j = 0; j < 8; ++j) {
        acc[j] += __shfl_xor(acc[j], 16);
        acc[j] += __shfl_xor(acc[j], 32);
    }
    if (slot == 0) {                                  // lanes 0..15
        for (int o = 0; o < novf; ++o) {              // fold overflow (novf~0)
            int4 mm = ovf[o];
            if (mm.x == g) {
                float v = __int_as_float(mm.z);
                uint4 x = pk[(size_t)mm.y * 16 + q];
                acc[0] += v * bf_lo(x.x); acc[1] += v * bf_hi(x.x);
                acc[2] += v * bf_lo(x.y); acc[3] += v * bf_hi(x.y);
                acc[4] += v * bf_lo(x.z); acc[5] += v * bf_hi(x.z);
                acc[6] += v * bf_lo(x.w); acc[7] += v * bf_hi(x.w);
            }
        }
        const float* hp = h0 + (size_t)g * D + q * 8;
        float4 ha = *(const float4*)(hp);
        float4 hb = *(const float4*)(hp + 4);
        float* sp = support + (size_t)g * D + q * 8;
        float4 sa, sb;
        sa.x = oma * acc[0] + alpha * ha.x;
        sa.y = oma * acc[1] + alpha * ha.y;
        sa.z = oma * acc[2] + alpha * ha.z;
        sa.w = oma * acc[3] + alpha * ha.w;
        sb.x = oma * acc[4] + alpha * hb.x;
        sb.y = oma * acc[5] + alpha * hb.y;
        sb.z = oma * acc[6] + alpha * hb.z;
        sb.w = oma * acc[7] + alpha * hb.w;
        *(float4*)(sp) = sa;
        *(float4*)(sp + 4) = sb;
    }
}

// ---------------------------------------------------------------------------
// K4: MFMA bf16 in-place GEMM + epilogue on d_out (proven form).
//   data[r] (out) = theta * bf16(data[r]) @ bf16(W) + (1-theta) * data[r]
// LDS: sA 64x136 bf16 + sB (W^T) 128x136 bf16 = 52 KB -> 3 blocks/CU.
// ---------------------------------------------------------------------------
__global__ __launch_bounds__(256) void gemm_mfma(
    const ushort* __restrict__ wt,
    const float* __restrict__ lamda_p,
    const int* __restrict__ l_p,
    float* __restrict__ data)
{
    constexpr int SP = 136;                // padded LDS row stride (bf16 units)
    __shared__ ushort sA[64 * SP];         // 17,408 B
    __shared__ ushort sB[128 * SP];        // 34,816 B

    const int tid = threadIdx.x;
    const float lamda = *lamda_p;
    const float theta = logf(lamda / (float)(*l_p) + 1.0f);
    const float omt = 1.0f - theta;
    const int row0 = blockIdx.x * 64;

    // stage W^T: 2048 uint4 (8 bf16 each) over 256 threads -> 8 each
    #pragma unroll
    for (int j = 0; j < 8; ++j) {
        int idx = j * 256 + tid;
        int n  = idx >> 4;
        int k8 = (idx & 15) << 3;
        *(uint4*)(&sB[n * SP + k8]) = ((const uint4*)wt)[idx];
    }
    // stage A tile: support fp32 -> bf16. 2048 float4 groups -> 8 each.
    #pragma unroll
    for (int j = 0; j < 8; ++j) {
        int idx = j * 256 + tid;
        int rr = idx >> 5;
        int c4 = (idx & 31) << 2;
        int g = row0 + rr;
        float4 s = make_float4(0.f, 0.f, 0.f, 0.f);
        if (g < N_NODES) s = *(const float4*)(data + (size_t)g * D + c4);
        uint2 pkv;
        pkv.x = bf16rn(s.x) | (bf16rn(s.y) << 16);
        pkv.y = bf16rn(s.z) | (bf16rn(s.w) << 16);
        *(uint2*)(&sA[rr * SP + c4]) = pkv;
    }
    __syncthreads();

    const int wave = tid >> 6;
    const int lane = tid & 63;
    const int m    = lane & 15;
    const int quad = lane >> 4;
    const int arow = wave * 16 + m;

    f32x4 acc[8] = {};                      // 8 N-tiles of 16 cols
    #pragma unroll
    for (int kb = 0; kb < 4; ++kb) {
        bf16x8 a = *(const bf16x8*)(&sA[arow * SP + kb * 32 + quad * 8]);
        #pragma unroll
        for (int nt = 0; nt < 8; ++nt) {
            bf16x8 b = *(const bf16x8*)(&sB[(nt * 16 + m) * SP + kb * 32 + quad * 8]);
            acc[nt] = __builtin_amdgcn_mfma_f32_16x16x32_bf16(a, b, acc[nt], 0, 0, 0);
        }
    }

    // epilogue: rows row0 + wave*16 + quad*4 + i, col nt*16 + m
    const int gbase = row0 + wave * 16 + quad * 4;
    #pragma unroll
    for (int nt = 0; nt < 8; ++nt) {
        int colb = nt * 16 + m;
        #pragma unroll
        for (int i = 0; i < 4; ++i) {
            int g = gbase + i;
            if (g < N_NODES) {
                size_t off = (size_t)g * D + colb;
                float s = data[off];
                data[off] = theta * acc[nt][i] + omt * s;
            }
        }
    }
}

extern "C" void kernel_launch(void* const* d_in, const int* in_sizes, int n_in,
                              void* d_out, int out_size, void* d_ws, size_t ws_size,
                              hipStream_t stream) {
    const float* input  = (const float*)d_in[0];
    const float* h0     = (const float*)d_in[1];
    const float* vals   = (const float*)d_in[2];
    const float* weight = (const float*)d_in[3];
    const float* lamda  = (const float*)d_in[4];
    const float* alpha  = (const float*)d_in[5];
    const int*   row    = (const int*)d_in[6];
    const int*   col    = (const int*)d_in[7];
    const int*   l      = (const int*)d_in[8];
    float* out = (float*)d_out;

    char* ws = (char*)d_ws;
    int*      qcnt    = (int*)ws;
    int*      ovf_cnt = (int*)(ws + OFF_OVFCNT);
    uint2*    queue   = (uint2*)(ws + OFF_QUEUE);
    int*      cnt     = (int*)(ws + OFF_CNT);
    unsigned* bucket  = (unsigned*)(ws + OFF_BUCKET);
    int4*     ovf     = (int4*)(ws + OFF_OVF);
    unsigned* packed  = (unsigned*)(ws + OFF_PACKED);
    ushort*   wt      = (ushort*)(ws + OFF_WT);

    // zero qcnt + ovf_cnt only (16.4 KB -- cnt no longer needs zeroing:
    // bucket_build writes every count)
    hipMemsetAsync(ws, 0, OFF_QUEUE, stream);

    binsort_cast<<<BIN_BLOCKS + CAST_BLOCKS + 1, 256, 0, stream>>>(
        row, col, vals, input, weight, qcnt, queue, ovf_cnt, ovf, packed, wt);

    bucket_build<<<NBIN, 256, 0, stream>>>(queue, qcnt, ovf_cnt, ovf, cnt, bucket);

    int gatherb = (N_NODES + 3) / 4;                 // 12500 (4 waves/block)
    gather_support<<<gatherb, 256, 0, stream>>>(
        packed, h0, alpha, cnt, bucket, ovf_cnt, ovf, out);

    int gemmb = (N_NODES + 63) / 64;                 // 782
    gemm_mfma<<<gemmb, 256, 0, stream>>>(wt, lamda, l, out);
}